// Round 2
// baseline (8306.351 us; speedup 1.0000x reference)
//
#include <hip/hip_runtime.h>
#include <math.h>

#define B 8
#define L 4096
#define DM 1024
#define H 16
#define DH 64
#define SK 45
#define U 45
#define NCH 16
#define CHUNK 256

// ================= GEMM: C = A * W^T + bias =================
// A: (32768, 1024) row-major; W: (1024, 1024) row-major (out_feat, in_feat)
// mode 0: C row-major (32768,1024)
// mode 1: C[((b*H+h)*L + l)*64 + dh]  (head-split layout), h == bn since BN==64
#define BM 64
#define BN 64
#define BK 16

__global__ __launch_bounds__(256) void gemm_kernel(
    const float* __restrict__ A, const float* __restrict__ W,
    const float* __restrict__ bias, float* __restrict__ C, int mode)
{
  const int K = DM;
  int bm = blockIdx.x >> 4;   // 512 row tiles
  int bn = blockIdx.x & 15;   // 16 col tiles
  __shared__ float As[BK][BM];
  __shared__ float Bs[BK][BN];
  int tid = threadIdx.x;
  int tm = (tid & 15) << 2;
  int tn = (tid >> 4) << 2;
  int lr = tid >> 2;          // 0..63: row within tile for loading
  int lk = (tid & 3) << 2;    // 0,4,8,12: k offset for loading
  const float* Ab = A + (size_t)(bm * BM + lr) * K + lk;
  const float* Wb = W + (size_t)(bn * BN + lr) * K + lk;
  float acc[4][4] = {};
  for (int k0 = 0; k0 < K; k0 += BK) {
    float4 av = *(const float4*)(Ab + k0);
    float4 wv = *(const float4*)(Wb + k0);
    __syncthreads();
    As[lk + 0][lr] = av.x; As[lk + 1][lr] = av.y; As[lk + 2][lr] = av.z; As[lk + 3][lr] = av.w;
    Bs[lk + 0][lr] = wv.x; Bs[lk + 1][lr] = wv.y; Bs[lk + 2][lr] = wv.z; Bs[lk + 3][lr] = wv.w;
    __syncthreads();
#pragma unroll
    for (int kk = 0; kk < BK; ++kk) {
      float4 a = *(const float4*)&As[kk][tm];
      float4 b = *(const float4*)&Bs[kk][tn];
      acc[0][0] += a.x * b.x; acc[0][1] += a.x * b.y; acc[0][2] += a.x * b.z; acc[0][3] += a.x * b.w;
      acc[1][0] += a.y * b.x; acc[1][1] += a.y * b.y; acc[1][2] += a.y * b.z; acc[1][3] += a.y * b.w;
      acc[2][0] += a.z * b.x; acc[2][1] += a.z * b.y; acc[2][2] += a.z * b.z; acc[2][3] += a.z * b.w;
      acc[3][0] += a.w * b.x; acc[3][1] += a.w * b.y; acc[3][2] += a.w * b.z; acc[3][3] += a.w * b.w;
    }
  }
  if (mode == 0) {
#pragma unroll
    for (int i = 0; i < 4; ++i) {
      int row = bm * BM + tm + i;
      int col0 = bn * BN + tn;
#pragma unroll
      for (int j = 0; j < 4; ++j)
        C[(size_t)row * DM + col0 + j] = acc[i][j] + bias[col0 + j];
    }
  } else {
    int h = bn;  // BN==64==DH, N-tiles align with heads
#pragma unroll
    for (int i = 0; i < 4; ++i) {
      int row = bm * BM + tm + i;
      int b_ = row >> 12;        // /L
      int l = row & (L - 1);
      size_t base = ((size_t)(b_ * H + h) * L + l) * DH;
#pragma unroll
      for (int j = 0; j < 4; ++j)
        C[base + tn + j] = acc[i][j] + bias[h * DH + tn + j];
    }
  }
}

// ============ M-score: M[b,h,l] = max_s(Q.Ks) - sum_s(Q.Ks)/L ============
__global__ __launch_bounds__(256) void mscore_kernel(
    const float* __restrict__ Q, const float* __restrict__ Kmat,
    const int* __restrict__ sidx, float* __restrict__ Mout)
{
  int wid = blockIdx.x * 4 + (threadIdx.x >> 6);  // one wave per (b,h,l)
  int lane = threadIdx.x & 63;
  int l = wid & (L - 1);
  int bh = wid >> 12;
  float q = Q[((size_t)bh * L + l) * DH + lane];
  const float* Kb = Kmat + (size_t)bh * L * DH;
  float mx = -INFINITY, sm = 0.f;
  for (int s = 0; s < SK; ++s) {
    int pos = sidx[l * SK + s];
    float p = q * Kb[(size_t)pos * DH + lane];
#pragma unroll
    for (int off = 32; off > 0; off >>= 1) p += __shfl_xor(p, off);
    mx = fmaxf(mx, p);
    sm += p;
  }
  if (lane == 0) Mout[wid] = mx - sm * (1.0f / (float)L);
}

// ============ top-k (U=45) per (b,h), also builds pos->u map ============
__global__ __launch_bounds__(256) void topk_kernel(
    const float* __restrict__ Mbuf, int* __restrict__ topk, int* __restrict__ map)
{
  int bh = blockIdx.x;
  int tid = threadIdx.x;
  __shared__ float vals[L];
  __shared__ float rv[256];
  __shared__ int ri[256];
  for (int i = tid; i < L; i += 256) {
    vals[i] = Mbuf[(size_t)bh * L + i];
    map[(size_t)bh * L + i] = -1;
  }
  __syncthreads();
  for (int u = 0; u < U; ++u) {
    float bv = -INFINITY;
    int bi = 1 << 30;
    for (int i = tid; i < L; i += 256) {
      float v = vals[i];
      if (v > bv || (v == bv && i < bi)) { bv = v; bi = i; }
    }
    rv[tid] = bv; ri[tid] = bi;
    __syncthreads();
    for (int s = 128; s > 0; s >>= 1) {
      if (tid < s) {
        float ov = rv[tid + s]; int oi = ri[tid + s];
        if (ov > rv[tid] || (ov == rv[tid] && oi < ri[tid])) { rv[tid] = ov; ri[tid] = oi; }
      }
      __syncthreads();
    }
    if (tid == 0) {
      int p = ri[0];
      topk[bh * U + u] = p;
      map[(size_t)bh * L + p] = u;
      vals[p] = -INFINITY;
    }
    __syncthreads();
  }
}

// ==== fused scores -> causal softmax -> upd, one block per (b,h,u) ====
__global__ __launch_bounds__(256) void attn_kernel(
    const float* __restrict__ Q, const float* __restrict__ Kmat,
    const float* __restrict__ V, const int* __restrict__ topk,
    float* __restrict__ upd)
{
  int u = blockIdx.x % U;
  int bh = blockIdx.x / U;
  int tid = threadIdx.x;
  int m = topk[bh * U + u];
  __shared__ float q[DH];
  __shared__ float sc[L];
  __shared__ float red[256];
  __shared__ float vpart[4][DH];
  if (tid < DH) q[tid] = Q[((size_t)bh * L + m) * DH + tid];
  __syncthreads();
  const float scale = 0.125f;  // 1/sqrt(64)
  // pass 1: scores for k <= m
  for (int k = tid; k <= m; k += 256) {
    const float4* kr = (const float4*)(Kmat + ((size_t)bh * L + k) * DH);
    float d = 0.f;
#pragma unroll
    for (int i = 0; i < 16; ++i) {
      float4 kv = kr[i];
      float4 qv = *(const float4*)&q[i * 4];
      d += kv.x * qv.x + kv.y * qv.y + kv.z * qv.z + kv.w * qv.w;
    }
    sc[k] = d * scale;
  }
  __syncthreads();
  // max
  float lm = -INFINITY;
  for (int k = tid; k <= m; k += 256) lm = fmaxf(lm, sc[k]);
  red[tid] = lm;
  __syncthreads();
  for (int s = 128; s > 0; s >>= 1) {
    if (tid < s) red[tid] = fmaxf(red[tid], red[tid + s]);
    __syncthreads();
  }
  float smax = red[0];
  __syncthreads();
  // exp + sum
  float ls = 0.f;
  for (int k = tid; k <= m; k += 256) {
    float e = expf(sc[k] - smax);
    sc[k] = e;
    ls += e;
  }
  red[tid] = ls;
  __syncthreads();
  for (int s = 128; s > 0; s >>= 1) {
    if (tid < s) red[tid] += red[tid + s];
    __syncthreads();
  }
  float ssum = red[0];
  __syncthreads();
  // weighted V accumulation
  int g = tid >> 6, d = tid & 63;
  float acc = 0.f;
  for (int k = g; k <= m; k += 4)
    acc += sc[k] * V[((size_t)bh * L + k) * DH + d];
  vpart[g][d] = acc;
  __syncthreads();
  if (tid < DH) {
    float t = vpart[0][tid] + vpart[1][tid] + vpart[2][tid] + vpart[3][tid];
    upd[((size_t)bh * U + u) * DH + tid] = t / ssum;
  }
}

// ================= cumsum(V) over l, 3-phase, + scatter upd =================
__global__ __launch_bounds__(256) void cumsum_p1(const float* __restrict__ V, float* __restrict__ chunks)
{
  int wid = blockIdx.x * 4 + (threadIdx.x >> 6);  // (bh, c)
  int lane = threadIdx.x & 63;
  int c = wid & (NCH - 1);
  int bh = wid >> 4;
  const float* vb = V + ((size_t)bh * L + c * CHUNK) * DH + lane;
  float s = 0.f;
  for (int j = 0; j < CHUNK; ++j) s += vb[(size_t)j * DH];
  chunks[((size_t)bh * NCH + c) * DH + lane] = s;
}

__global__ __launch_bounds__(256) void cumsum_p2(float* __restrict__ chunks)
{
  int t = blockIdx.x * 256 + threadIdx.x;  // B*H*DH = 8192 threads
  int bh = t >> 6;
  int d = t & 63;
  float run = 0.f;
  for (int c = 0; c < NCH; ++c) {
    size_t idx = ((size_t)bh * NCH + c) * DH + d;
    float v = chunks[idx];
    chunks[idx] = run;  // exclusive
    run += v;
  }
}

__global__ __launch_bounds__(256) void cumsum_p3(
    const float* __restrict__ V, const float* __restrict__ chunks,
    const int* __restrict__ map, const float* __restrict__ upd,
    float* __restrict__ ctx)
{
  int wid = blockIdx.x * 4 + (threadIdx.x >> 6);
  int lane = threadIdx.x & 63;
  int c = wid & (NCH - 1);
  int bh = wid >> 4;
  int b_ = bh / H, h = bh % H;
  float acc = chunks[((size_t)bh * NCH + c) * DH + lane];
  const float* vb = V + ((size_t)bh * L + c * CHUNK) * DH + lane;
  for (int j = 0; j < CHUNK; ++j) {
    int pos = c * CHUNK + j;
    acc += vb[(size_t)j * DH];
    int uu = map[(size_t)bh * L + pos];
    float val = (uu >= 0) ? upd[((size_t)bh * U + uu) * DH + lane] : acc;
    ctx[((size_t)b_ * L + pos) * DM + h * DH + lane] = val;
  }
}

// ============================ launch ============================
extern "C" void kernel_launch(void* const* d_in, const int* in_sizes, int n_in,
                              void* d_out, int out_size, void* d_ws, size_t ws_size,
                              hipStream_t stream) {
  const float* x   = (const float*)d_in[0];
  const int* sidx  = (const int*)d_in[1];
  const float* Wq  = (const float*)d_in[2];
  const float* bq  = (const float*)d_in[3];
  const float* Wk  = (const float*)d_in[4];
  const float* bk  = (const float*)d_in[5];
  const float* Wv  = (const float*)d_in[6];
  const float* bv  = (const float*)d_in[7];
  const float* Wo  = (const float*)d_in[8];
  const float* bo  = (const float*)d_in[9];
  float* out = (float*)d_out;

  const size_t NQKV = (size_t)B * H * L * DH;  // 33,554,432 floats = 128 MB

  // Workspace layout (~262 MB total):
  //   Q buffer doubles as ctx after attn_kernel (Q dead by then).
  //   V lives in d_out (dead before the final out-GEMM overwrites d_out).
  float* Q    = (float*)d_ws;          // 128 MB, later reused as ctx
  float* Kb   = Q + NQKV;              // 128 MB
  float* Mbuf = Kb + NQKV;             // 2 MB
  int* map    = (int*)(Mbuf + (size_t)B * H * L);          // 2 MB
  int* topk   = map + (size_t)B * H * L;                   // ~23 KB
  float* upd  = (float*)(topk + ((B * H * U + 63) & ~63)); // 1.4 MB
  float* chunks = upd + (size_t)B * H * U * DH;            // 0.5 MB
  float* V    = out;                   // alias d_out as V scratch
  float* ctx  = Q;                     // alias Q buffer as ctx

  // 1-3: Q/K/V projections (head-split layout)
  gemm_kernel<<<8192, 256, 0, stream>>>(x, Wq, bq, Q, 1);
  gemm_kernel<<<8192, 256, 0, stream>>>(x, Wk, bk, Kb, 1);
  gemm_kernel<<<8192, 256, 0, stream>>>(x, Wv, bv, V, 1);
  // 4: sparsity measurement
  mscore_kernel<<<(B * H * L) / 4, 256, 0, stream>>>(Q, Kb, sidx, Mbuf);
  // 5: top-k selection + scatter map
  topk_kernel<<<B * H, 256, 0, stream>>>(Mbuf, topk, map);
  // 6: fused scores/softmax/upd (Q dead after this)
  attn_kernel<<<B * H * U, 256, 0, stream>>>(Q, Kb, V, topk, upd);
  // 7-9: cumsum(V) + scatter upd into context (b,l,h,d) layout
  cumsum_p1<<<(B * H * NCH) / 4, 256, 0, stream>>>(V, chunks);
  cumsum_p2<<<(B * H * DH) / 256, 256, 0, stream>>>(chunks);
  cumsum_p3<<<(B * H * NCH) / 4, 256, 0, stream>>>(V, chunks, map, upd, ctx);
  // 10: output projection (reads ctx, overwrites d_out; V no longer needed)
  gemm_kernel<<<8192, 256, 0, stream>>>(ctx, Wo, bo, out, 0);
}

// Round 3
// 5769.728 us; speedup vs baseline: 1.4396x; 1.4396x over previous
//
#include <hip/hip_runtime.h>
#include <math.h>

#define B 8
#define L 4096
#define DM 1024
#define H 16
#define DH 64
#define SK 45
#define U 45
#define NCH 16
#define CHUNK 256
#define NSPLIT 8
#define SLEN (L / NSPLIT)
#define TILE 64
#define UPAD 48
#define QROW 72

typedef __attribute__((ext_vector_type(4))) float f32x4;
typedef __attribute__((ext_vector_type(8))) short short8;

static __device__ __forceinline__ unsigned short f2bf(float f) {
  union { float f; unsigned int u; } v; v.f = f;
  unsigned int r = v.u + 0x7fffu + ((v.u >> 16) & 1u);
  return (unsigned short)(r >> 16);
}

// ================= GEMM: C = A * W^T + bias =================
#define BM 64
#define BN 64
#define BK 16

__global__ __launch_bounds__(256) void gemm_kernel(
    const float* __restrict__ A, const float* __restrict__ W,
    const float* __restrict__ bias, float* __restrict__ C, int mode)
{
  const int K = DM;
  int bm = blockIdx.x >> 4;
  int bn = blockIdx.x & 15;
  __shared__ float As[BK][BM];
  __shared__ float Bs[BK][BN];
  int tid = threadIdx.x;
  int tm = (tid & 15) << 2;
  int tn = (tid >> 4) << 2;
  int lr = tid >> 2;
  int lk = (tid & 3) << 2;
  const float* Ab = A + (size_t)(bm * BM + lr) * K + lk;
  const float* Wb = W + (size_t)(bn * BN + lr) * K + lk;
  float acc[4][4] = {};
  for (int k0 = 0; k0 < K; k0 += BK) {
    float4 av = *(const float4*)(Ab + k0);
    float4 wv = *(const float4*)(Wb + k0);
    __syncthreads();
    As[lk + 0][lr] = av.x; As[lk + 1][lr] = av.y; As[lk + 2][lr] = av.z; As[lk + 3][lr] = av.w;
    Bs[lk + 0][lr] = wv.x; Bs[lk + 1][lr] = wv.y; Bs[lk + 2][lr] = wv.z; Bs[lk + 3][lr] = wv.w;
    __syncthreads();
#pragma unroll
    for (int kk = 0; kk < BK; ++kk) {
      float4 a = *(const float4*)&As[kk][tm];
      float4 b = *(const float4*)&Bs[kk][tn];
      acc[0][0] += a.x * b.x; acc[0][1] += a.x * b.y; acc[0][2] += a.x * b.z; acc[0][3] += a.x * b.w;
      acc[1][0] += a.y * b.x; acc[1][1] += a.y * b.y; acc[1][2] += a.y * b.z; acc[1][3] += a.y * b.w;
      acc[2][0] += a.z * b.x; acc[2][1] += a.z * b.y; acc[2][2] += a.z * b.z; acc[2][3] += a.z * b.w;
      acc[3][0] += a.w * b.x; acc[3][1] += a.w * b.y; acc[3][2] += a.w * b.z; acc[3][3] += a.w * b.w;
    }
  }
  if (mode == 0) {
#pragma unroll
    for (int i = 0; i < 4; ++i) {
      int row = bm * BM + tm + i;
      int col0 = bn * BN + tn;
#pragma unroll
      for (int j = 0; j < 4; ++j)
        C[(size_t)row * DM + col0 + j] = acc[i][j] + bias[col0 + j];
    }
  } else {
    int h = bn;
#pragma unroll
    for (int i = 0; i < 4; ++i) {
      int row = bm * BM + tm + i;
      int b_ = row >> 12;
      int l = row & (L - 1);
      size_t base = ((size_t)(b_ * H + h) * L + l) * DH;
#pragma unroll
      for (int j = 0; j < 4; ++j)
        C[base + tn + j] = acc[i][j] + bias[h * DH + tn + j];
    }
  }
}

// ============ M-score ============
__global__ __launch_bounds__(256) void mscore_kernel(
    const float* __restrict__ Q, const float* __restrict__ Kmat,
    const int* __restrict__ sidx, float* __restrict__ Mout)
{
  int wid = blockIdx.x * 4 + (threadIdx.x >> 6);
  int lane = threadIdx.x & 63;
  int l = wid & (L - 1);
  int bh = wid >> 12;
  float q = Q[((size_t)bh * L + l) * DH + lane];
  const float* Kb = Kmat + (size_t)bh * L * DH;
  float mx = -INFINITY, sm = 0.f;
  for (int s = 0; s < SK; ++s) {
    int pos = sidx[l * SK + s];
    float p = q * Kb[(size_t)pos * DH + lane];
#pragma unroll
    for (int off = 32; off > 0; off >>= 1) p += __shfl_xor(p, off);
    mx = fmaxf(mx, p);
    sm += p;
  }
  if (lane == 0) Mout[wid] = mx - sm * (1.0f / (float)L);
}

// ============ top-k (U=45) per (b,h) ============
__global__ __launch_bounds__(256) void topk_kernel(
    const float* __restrict__ Mbuf, int* __restrict__ topk, int* __restrict__ map)
{
  int bh = blockIdx.x;
  int tid = threadIdx.x;
  __shared__ float vals[L];
  __shared__ float rv[256];
  __shared__ int ri[256];
  for (int i = tid; i < L; i += 256) {
    vals[i] = Mbuf[(size_t)bh * L + i];
    map[(size_t)bh * L + i] = -1;
  }
  __syncthreads();
  for (int u = 0; u < U; ++u) {
    float bv = -INFINITY;
    int bi = 1 << 30;
    for (int i = tid; i < L; i += 256) {
      float v = vals[i];
      if (v > bv || (v == bv && i < bi)) { bv = v; bi = i; }
    }
    rv[tid] = bv; ri[tid] = bi;
    __syncthreads();
    for (int s = 128; s > 0; s >>= 1) {
      if (tid < s) {
        float ov = rv[tid + s]; int oi = ri[tid + s];
        if (ov > rv[tid] || (ov == rv[tid] && oi < ri[tid])) { rv[tid] = ov; ri[tid] = oi; }
      }
      __syncthreads();
    }
    if (tid == 0) {
      int p = ri[0];
      topk[bh * U + u] = p;
      map[(size_t)bh * L + p] = u;
      vals[p] = -INFINITY;
    }
    __syncthreads();
  }
}

// ==== flash-decoding attn: per (b,h,split) partials via MFMA ====
__global__ __launch_bounds__(256) void attn_partial(
    const float* __restrict__ Q, const float* __restrict__ Kmat,
    const float* __restrict__ V, const int* __restrict__ topk,
    float* __restrict__ Opart, float* __restrict__ Mpart, float* __restrict__ Lpart)
{
  __shared__ __align__(16) unsigned short qs[UPAD][QROW];
  __shared__ __align__(16) unsigned short Ks[TILE][QROW];
  __shared__ __align__(16) unsigned short Vt[DH][QROW];
  __shared__ __align__(16) unsigned short ps[4][16][QROW];
  __shared__ int ms[UPAD];

  int tid = threadIdx.x;
  int bh = blockIdx.x / NSPLIT;
  int s  = blockIdx.x % NSPLIT;
  int kstart = s * SLEN;

  // ---- stage q rows (48, zero-padded) + ms ----
  {
    int u = tid & 63, c = tid >> 6;
    if (u < UPAD) {
      int mu = (u < U) ? topk[bh * U + u] : -1;
      if (c == 0) ms[u] = mu;
      unsigned int pk[8];
      if (mu >= 0) {
        const float4* src = (const float4*)(Q + ((size_t)bh * L + mu) * DH + c * 16);
#pragma unroll
        for (int j = 0; j < 4; ++j) {
          float4 f = src[j];
          pk[j * 2 + 0] = (unsigned)f2bf(f.x) | ((unsigned)f2bf(f.y) << 16);
          pk[j * 2 + 1] = (unsigned)f2bf(f.z) | ((unsigned)f2bf(f.w) << 16);
        }
      } else {
#pragma unroll
        for (int j = 0; j < 8; ++j) pk[j] = 0;
      }
      uint4* dst = (uint4*)&qs[u][c * 16];
      dst[0] = make_uint4(pk[0], pk[1], pk[2], pk[3]);
      dst[1] = make_uint4(pk[4], pk[5], pk[6], pk[7]);
    }
  }
  __syncthreads();

  int bmax = -1;
  for (int i = 0; i < UPAD; ++i) bmax = max(bmax, ms[i]);
  int kend = min(SLEN, bmax + 1 - kstart);
  int ntiles = (kend > 0) ? (kend + TILE - 1) / TILE : 0;

  int lane = tid & 63;
  int w = tid >> 6;
  int ubase = w * 16;
  int col = lane & 15;
  int quad = lane >> 4;

  int mrow[4];
  float Mr[4], Lr[4];
  f32x4 Oacc[4];
#pragma unroll
  for (int ng = 0; ng < 4; ++ng) Oacc[ng] = (f32x4){0.f, 0.f, 0.f, 0.f};
#pragma unroll
  for (int r = 0; r < 4; ++r) {
    int uu = ubase + quad * 4 + r;
    mrow[r] = (w < 3) ? ms[uu] : -1;
    Mr[r] = -1e30f; Lr[r] = 0.f;
  }
  int gq = max(max(mrow[0], mrow[1]), max(mrow[2], mrow[3]));
  gq = max(gq, __shfl_xor(gq, 16));
  gq = max(gq, __shfl_xor(gq, 32));

  for (int t = 0; t < ntiles; ++t) {
    int k0 = kstart + t * TILE;
    __syncthreads();
    // stage K tile (row-major bf16) and V tile (transposed bf16)
    {
      int kr = tid & 63, dc = tid >> 6;
      const float4* ksrc = (const float4*)(Kmat + ((size_t)bh * L + k0 + kr) * DH + dc * 16);
      unsigned int pk[8];
#pragma unroll
      for (int j = 0; j < 4; ++j) {
        float4 f = ksrc[j];
        pk[j * 2 + 0] = (unsigned)f2bf(f.x) | ((unsigned)f2bf(f.y) << 16);
        pk[j * 2 + 1] = (unsigned)f2bf(f.z) | ((unsigned)f2bf(f.w) << 16);
      }
      uint4* kd = (uint4*)&Ks[kr][dc * 16];
      kd[0] = make_uint4(pk[0], pk[1], pk[2], pk[3]);
      kd[1] = make_uint4(pk[4], pk[5], pk[6], pk[7]);
      const float4* vsrc = (const float4*)(V + ((size_t)bh * L + k0 + kr) * DH + dc * 16);
#pragma unroll
      for (int j = 0; j < 4; ++j) {
        float4 f = vsrc[j];
        Vt[dc * 16 + j * 4 + 0][kr] = f2bf(f.x);
        Vt[dc * 16 + j * 4 + 1][kr] = f2bf(f.y);
        Vt[dc * 16 + j * 4 + 2][kr] = f2bf(f.z);
        Vt[dc * 16 + j * 4 + 3][kr] = f2bf(f.w);
      }
    }
    __syncthreads();
    if (w == 3 || k0 > gq) continue;

    // ---- QK^T: s[u][kpos], m=u n=kpos k=d ----
    f32x4 sacc[4];
#pragma unroll
    for (int ng = 0; ng < 4; ++ng) sacc[ng] = (f32x4){0.f, 0.f, 0.f, 0.f};
#pragma unroll
    for (int kg = 0; kg < 2; ++kg) {
      short8 af = *(const short8*)&qs[ubase + col][kg * 32 + quad * 8];
#pragma unroll
      for (int ng = 0; ng < 4; ++ng) {
        short8 bf_ = *(const short8*)&Ks[ng * 16 + col][kg * 32 + quad * 8];
        sacc[ng] = __builtin_amdgcn_mfma_f32_16x16x32_bf16(af, bf_, sacc[ng], 0, 0, 0);
      }
    }
    // ---- online softmax per row r (u = ubase + quad*4 + r) ----
#pragma unroll
    for (int r = 0; r < 4; ++r) {
      int mu = mrow[r];
      float msv[4];
      float tm = -1e30f;
#pragma unroll
      for (int ng = 0; ng < 4; ++ng) {
        int kpos = k0 + ng * 16 + col;
        float sv = (kpos <= mu) ? sacc[ng][r] * 0.125f : -1e30f;
        msv[ng] = sv;
        tm = fmaxf(tm, sv);
      }
      tm = fmaxf(tm, __shfl_xor(tm, 1));
      tm = fmaxf(tm, __shfl_xor(tm, 2));
      tm = fmaxf(tm, __shfl_xor(tm, 4));
      tm = fmaxf(tm, __shfl_xor(tm, 8));
      float newM = fmaxf(Mr[r], tm);
      float alpha = __expf(Mr[r] - newM);
      float psum = 0.f;
      float pv[4];
#pragma unroll
      for (int ng = 0; ng < 4; ++ng) {
        float p = (msv[ng] > -1e29f) ? __expf(msv[ng] - newM) : 0.f;
        pv[ng] = p;
        psum += p;
      }
      psum += __shfl_xor(psum, 1);
      psum += __shfl_xor(psum, 2);
      psum += __shfl_xor(psum, 4);
      psum += __shfl_xor(psum, 8);
      Lr[r] = Lr[r] * alpha + psum;
      Mr[r] = newM;
#pragma unroll
      for (int ng = 0; ng < 4; ++ng) Oacc[ng][r] *= alpha;
#pragma unroll
      for (int ng = 0; ng < 4; ++ng)
        ps[w][quad * 4 + r][ng * 16 + col] = f2bf(pv[ng]);
    }
    // ---- PV: O[u][d] += p[u][kpos] * V[kpos][d], m=u n=d k=kpos ----
#pragma unroll
    for (int kg = 0; kg < 2; ++kg) {
      short8 pf = *(const short8*)&ps[w][col][kg * 32 + quad * 8];
#pragma unroll
      for (int ng = 0; ng < 4; ++ng) {
        short8 vf = *(const short8*)&Vt[ng * 16 + col][kg * 32 + quad * 8];
        Oacc[ng] = __builtin_amdgcn_mfma_f32_16x16x32_bf16(pf, vf, Oacc[ng], 0, 0, 0);
      }
    }
  }

  if (w < 3) {
    size_t base = ((size_t)bh * NSPLIT + s) * UPAD;
#pragma unroll
    for (int r = 0; r < 4; ++r) {
      int uu = ubase + quad * 4 + r;
#pragma unroll
      for (int ng = 0; ng < 4; ++ng)
        Opart[(base + uu) * DH + ng * 16 + col] = Oacc[ng][r];
      if (col == 0) { Mpart[base + uu] = Mr[r]; Lpart[base + uu] = Lr[r]; }
    }
  }
}

// ==== combine split partials -> upd ====
__global__ __launch_bounds__(256) void attn_combine(
    const float* __restrict__ Opart, const float* __restrict__ Mpart,
    const float* __restrict__ Lpart, float* __restrict__ upd)
{
  int idx = blockIdx.x * 4 + (threadIdx.x >> 6);
  int lane = threadIdx.x & 63;
  int bh = idx / U, u = idx % U;
  size_t base = (size_t)bh * NSPLIT * UPAD + u;
  float Ms[NSPLIT];
  float Mg = -1e30f;
#pragma unroll
  for (int ss = 0; ss < NSPLIT; ++ss) {
    Ms[ss] = Mpart[base + ss * UPAD];
    Mg = fmaxf(Mg, Ms[ss]);
  }
  float acc = 0.f, lsum = 0.f;
#pragma unroll
  for (int ss = 0; ss < NSPLIT; ++ss) {
    float wgt = __expf(Ms[ss] - Mg);
    acc += wgt * Opart[(base + ss * UPAD) * DH + lane];
    lsum += wgt * Lpart[base + ss * UPAD];
  }
  upd[((size_t)bh * U + u) * DH + lane] = acc / lsum;
}

// ================= cumsum(V) + scatter =================
__global__ __launch_bounds__(256) void cumsum_p1(const float* __restrict__ V, float* __restrict__ chunks)
{
  int wid = blockIdx.x * 4 + (threadIdx.x >> 6);
  int lane = threadIdx.x & 63;
  int c = wid & (NCH - 1);
  int bh = wid >> 4;
  const float* vb = V + ((size_t)bh * L + c * CHUNK) * DH + lane;
  float s = 0.f;
  for (int j = 0; j < CHUNK; ++j) s += vb[(size_t)j * DH];
  chunks[((size_t)bh * NCH + c) * DH + lane] = s;
}

__global__ __launch_bounds__(256) void cumsum_p2(float* __restrict__ chunks)
{
  int t = blockIdx.x * 256 + threadIdx.x;
  int bh = t >> 6;
  int d = t & 63;
  float run = 0.f;
  for (int c = 0; c < NCH; ++c) {
    size_t idx = ((size_t)bh * NCH + c) * DH + d;
    float v = chunks[idx];
    chunks[idx] = run;
    run += v;
  }
}

__global__ __launch_bounds__(256) void cumsum_p3(
    const float* __restrict__ V, const float* __restrict__ chunks,
    const int* __restrict__ map, const float* __restrict__ upd,
    float* __restrict__ ctx)
{
  int wid = blockIdx.x * 4 + (threadIdx.x >> 6);
  int lane = threadIdx.x & 63;
  int c = wid & (NCH - 1);
  int bh = wid >> 4;
  int b_ = bh / H, h = bh % H;
  float acc = chunks[((size_t)bh * NCH + c) * DH + lane];
  const float* vb = V + ((size_t)bh * L + c * CHUNK) * DH + lane;
  for (int j = 0; j < CHUNK; ++j) {
    int pos = c * CHUNK + j;
    acc += vb[(size_t)j * DH];
    int uu = map[(size_t)bh * L + pos];
    float val = (uu >= 0) ? upd[((size_t)bh * U + uu) * DH + lane] : acc;
    ctx[((size_t)b_ * L + pos) * DM + h * DH + lane] = val;
  }
}

// ============================ launch ============================
extern "C" void kernel_launch(void* const* d_in, const int* in_sizes, int n_in,
                              void* d_out, int out_size, void* d_ws, size_t ws_size,
                              hipStream_t stream) {
  const float* x   = (const float*)d_in[0];
  const int* sidx  = (const int*)d_in[1];
  const float* Wq  = (const float*)d_in[2];
  const float* bq  = (const float*)d_in[3];
  const float* Wk  = (const float*)d_in[4];
  const float* bk  = (const float*)d_in[5];
  const float* Wv  = (const float*)d_in[6];
  const float* bv  = (const float*)d_in[7];
  const float* Wo  = (const float*)d_in[8];
  const float* bo  = (const float*)d_in[9];
  float* out = (float*)d_out;

  const size_t NQKV = (size_t)B * H * L * DH;

  float* Q    = (float*)d_ws;          // 134 MB, reused as ctx after attn
  float* Kb   = Q + NQKV;              // 134 MB
  float* Mbuf = Kb + NQKV;
  int* map    = (int*)(Mbuf + (size_t)B * H * L);
  int* topk   = map + (size_t)B * H * L;
  float* upd  = (float*)(topk + ((B * H * U + 63) & ~63));
  float* chunks = upd + (size_t)B * H * U * DH;
  float* Opart  = chunks + (size_t)B * H * NCH * DH;                // 12.6 MB
  float* Mpart  = Opart + (size_t)B * H * NSPLIT * UPAD * DH;
  float* Lpart  = Mpart + (size_t)B * H * NSPLIT * UPAD;
  float* V    = out;                   // alias d_out as V scratch
  float* ctx  = Q;                     // alias Q buffer as ctx

  gemm_kernel<<<8192, 256, 0, stream>>>(x, Wq, bq, Q, 1);
  gemm_kernel<<<8192, 256, 0, stream>>>(x, Wk, bk, Kb, 1);
  gemm_kernel<<<8192, 256, 0, stream>>>(x, Wv, bv, V, 1);
  mscore_kernel<<<(B * H * L) / 4, 256, 0, stream>>>(Q, Kb, sidx, Mbuf);
  topk_kernel<<<B * H, 256, 0, stream>>>(Mbuf, topk, map);
  attn_partial<<<B * H * NSPLIT, 256, 0, stream>>>(Q, Kb, V, topk, Opart, Mpart, Lpart);
  attn_combine<<<(B * H * U) / 4, 256, 0, stream>>>(Opart, Mpart, Lpart, upd);
  cumsum_p1<<<(B * H * NCH) / 4, 256, 0, stream>>>(V, chunks);
  cumsum_p2<<<(B * H * DH) / 256, 256, 0, stream>>>(chunks);
  cumsum_p3<<<(B * H * NCH) / 4, 256, 0, stream>>>(V, chunks, map, upd, ctx);
  gemm_kernel<<<8192, 256, 0, stream>>>(ctx, Wo, bo, out, 0);
}

// Round 4
// 3514.110 us; speedup vs baseline: 2.3637x; 1.6419x over previous
//
#include <hip/hip_runtime.h>
#include <math.h>

#define B 8
#define L 4096
#define DM 1024
#define H 16
#define DH 64
#define SK 45
#define U 45
#define NCH 16
#define CHUNK 256
#define NSPLIT 8
#define SLEN (L / NSPLIT)
#define TILE 64
#define UPAD 48
#define QROW 72

typedef __attribute__((ext_vector_type(4))) float f32x4;
typedef __attribute__((ext_vector_type(8))) short short8;

static __device__ __forceinline__ unsigned short f2bf(float f) {
  union { float f; unsigned int u; } v; v.f = f;
  unsigned int r = v.u + 0x7fffu + ((v.u >> 16) & 1u);
  return (unsigned short)(r >> 16);
}
// pack hi16(a) into lo half, hi16(b) into hi half (bf16 truncation) — 1 VALU op
static __device__ __forceinline__ unsigned pkbf(float a, float b) {
  return __builtin_amdgcn_perm(__float_as_uint(b), __float_as_uint(a), 0x07060302u);
}

// ================= fp32 GEMM: C = A * W^T + bias (Q/K, selection-critical) ====
#define BM 64
#define BN 64
#define BK 16

__global__ __launch_bounds__(256) void gemm_kernel(
    const float* __restrict__ A, const float* __restrict__ W,
    const float* __restrict__ bias, float* __restrict__ C, int mode)
{
  const int K = DM;
  int bm = blockIdx.x >> 4;
  int bn = blockIdx.x & 15;
  __shared__ float As[BK][BM];
  __shared__ float Bs[BK][BN];
  int tid = threadIdx.x;
  int tm = (tid & 15) << 2;
  int tn = (tid >> 4) << 2;
  int lr = tid >> 2;
  int lk = (tid & 3) << 2;
  const float* Ab = A + (size_t)(bm * BM + lr) * K + lk;
  const float* Wb = W + (size_t)(bn * BN + lr) * K + lk;
  float acc[4][4] = {};
  for (int k0 = 0; k0 < K; k0 += BK) {
    float4 av = *(const float4*)(Ab + k0);
    float4 wv = *(const float4*)(Wb + k0);
    __syncthreads();
    As[lk + 0][lr] = av.x; As[lk + 1][lr] = av.y; As[lk + 2][lr] = av.z; As[lk + 3][lr] = av.w;
    Bs[lk + 0][lr] = wv.x; Bs[lk + 1][lr] = wv.y; Bs[lk + 2][lr] = wv.z; Bs[lk + 3][lr] = wv.w;
    __syncthreads();
#pragma unroll
    for (int kk = 0; kk < BK; ++kk) {
      float4 a = *(const float4*)&As[kk][tm];
      float4 b = *(const float4*)&Bs[kk][tn];
      acc[0][0] += a.x * b.x; acc[0][1] += a.x * b.y; acc[0][2] += a.x * b.z; acc[0][3] += a.x * b.w;
      acc[1][0] += a.y * b.x; acc[1][1] += a.y * b.y; acc[1][2] += a.y * b.z; acc[1][3] += a.y * b.w;
      acc[2][0] += a.z * b.x; acc[2][1] += a.z * b.y; acc[2][2] += a.z * b.z; acc[2][3] += a.z * b.w;
      acc[3][0] += a.w * b.x; acc[3][1] += a.w * b.y; acc[3][2] += a.w * b.z; acc[3][3] += a.w * b.w;
    }
  }
  if (mode == 0) {
#pragma unroll
    for (int i = 0; i < 4; ++i) {
      int row = bm * BM + tm + i;
      int col0 = bn * BN + tn;
#pragma unroll
      for (int j = 0; j < 4; ++j)
        C[(size_t)row * DM + col0 + j] = acc[i][j] + bias[col0 + j];
    }
  } else {
    int h = bn;
#pragma unroll
    for (int i = 0; i < 4; ++i) {
      int row = bm * BM + tm + i;
      int b_ = row >> 12;
      int l = row & (L - 1);
      size_t base = ((size_t)(b_ * H + h) * L + l) * DH;
#pragma unroll
      for (int j = 0; j < 4; ++j)
        C[base + tn + j] = acc[i][j] + bias[h * DH + tn + j];
    }
  }
}

// ============ bf16 MFMA GEMM: C = A * W^T + bias (value path) ============
// A: (32768, DM) fp32 row-major; W: (1024, DM) fp32 row-major.
// Staged to LDS as bf16 (perm-truncate). 128x128 tile, BK=32, 4 waves 2x2.
#define GTM 128
#define GTN 128
#define GTK 32
#define LSTR 40   // LDS row stride in shorts (+8 pad: 2-way bank aliasing = free)

__global__ __launch_bounds__(256) void mfma_gemm(
    const float* __restrict__ A, const float* __restrict__ W,
    const float* __restrict__ bias, float* __restrict__ C, int mode)
{
  __shared__ __align__(16) unsigned short As[GTM * LSTR];
  __shared__ __align__(16) unsigned short Bs[GTN * LSTR];
  int tid = threadIdx.x;
  int bm = blockIdx.x >> 3, bn = blockIdx.x & 7;
  int w = tid >> 6, lane = tid & 63;
  int col = lane & 15, quad = lane >> 4;
  int wm = (w >> 1) * 64, wn = (w & 1) * 64;
  int srow = tid >> 1, scol = (tid & 1) * 16;

  const float* ga = A + (size_t)(bm * GTM + srow) * DM + scol;
  const float* gb = W + (size_t)(bn * GTN + srow) * DM + scol;

  float4 ra[4], rb[4];
#pragma unroll
  for (int j = 0; j < 4; ++j) { ra[j] = *(const float4*)(ga + j * 4); rb[j] = *(const float4*)(gb + j * 4); }

  f32x4 acc[4][4];
#pragma unroll
  for (int i = 0; i < 4; ++i)
#pragma unroll
    for (int j = 0; j < 4; ++j) acc[i][j] = (f32x4){0.f, 0.f, 0.f, 0.f};

  for (int k = 0; k < DM / GTK; ++k) {
    __syncthreads();
    {
      unsigned pa[8], pb[8];
#pragma unroll
      for (int j = 0; j < 4; ++j) {
        pa[j * 2 + 0] = pkbf(ra[j].x, ra[j].y);
        pa[j * 2 + 1] = pkbf(ra[j].z, ra[j].w);
        pb[j * 2 + 0] = pkbf(rb[j].x, rb[j].y);
        pb[j * 2 + 1] = pkbf(rb[j].z, rb[j].w);
      }
      uint4* da = (uint4*)&As[srow * LSTR + scol];
      da[0] = make_uint4(pa[0], pa[1], pa[2], pa[3]);
      da[1] = make_uint4(pa[4], pa[5], pa[6], pa[7]);
      uint4* db = (uint4*)&Bs[srow * LSTR + scol];
      db[0] = make_uint4(pb[0], pb[1], pb[2], pb[3]);
      db[1] = make_uint4(pb[4], pb[5], pb[6], pb[7]);
    }
    __syncthreads();
    if (k + 1 < DM / GTK) {
      ga += GTK; gb += GTK;
#pragma unroll
      for (int j = 0; j < 4; ++j) { ra[j] = *(const float4*)(ga + j * 4); rb[j] = *(const float4*)(gb + j * 4); }
    }
    short8 af[4], bf[4];
#pragma unroll
    for (int t = 0; t < 4; ++t) {
      af[t] = *(const short8*)&As[(wm + t * 16 + col) * LSTR + quad * 8];
      bf[t] = *(const short8*)&Bs[(wn + t * 16 + col) * LSTR + quad * 8];
    }
#pragma unroll
    for (int mt = 0; mt < 4; ++mt)
#pragma unroll
      for (int nt = 0; nt < 4; ++nt)
        acc[mt][nt] = __builtin_amdgcn_mfma_f32_16x16x32_bf16(af[mt], bf[nt], acc[mt][nt], 0, 0, 0);
  }

  // epilogue: C row=m (A operand), col=n (B operand); row=quad*4+r, col=lane&15
#pragma unroll
  for (int mt = 0; mt < 4; ++mt) {
#pragma unroll
    for (int r = 0; r < 4; ++r) {
      int gm = bm * GTM + wm + mt * 16 + quad * 4 + r;
#pragma unroll
      for (int nt = 0; nt < 4; ++nt) {
        int gn = bn * GTN + wn + nt * 16 + col;
        float v = acc[mt][nt][r] + bias[gn];
        if (mode == 0) {
          C[(size_t)gm * DM + gn] = v;
        } else {
          int h = gn >> 6, dh = gn & 63;
          int b_ = gm >> 12, l = gm & (L - 1);
          C[((size_t)(b_ * H + h) * L + l) * DH + dh] = v;
        }
      }
    }
  }
}

// ============ M-score: lane-per-sample restructure ============
__global__ __launch_bounds__(256) void mscore_kernel(
    const float* __restrict__ Q, const float* __restrict__ Kmat,
    const int* __restrict__ sidx, float* __restrict__ Mout)
{
  __shared__ float4 qrow[4][16];
  int tid = threadIdx.x, w = tid >> 6, lane = tid & 63;
  int wid = blockIdx.x * 4 + w;
  int l = wid & (L - 1), bh = wid >> 12;
  if (lane < 16) qrow[w][lane] = *(const float4*)(Q + ((size_t)bh * L + l) * DH + lane * 4);
  __syncthreads();
  int s = (lane < SK) ? lane : (SK - 1);
  int pos = sidx[l * SK + s];
  const float* kr = Kmat + ((size_t)bh * L + pos) * DH;
  float acc = 0.f;
#pragma unroll
  for (int i = 0; i < 16; ++i) {
    float4 kv = *(const float4*)(kr + i * 4);
    float4 qv = qrow[w][i];
    acc += kv.x * qv.x + kv.y * qv.y + kv.z * qv.z + kv.w * qv.w;
  }
  float mx = (lane < SK) ? acc : -INFINITY;
  float sm = (lane < SK) ? acc : 0.f;
#pragma unroll
  for (int off = 1; off < 64; off <<= 1) {
    mx = fmaxf(mx, __shfl_xor(mx, off));
    sm += __shfl_xor(sm, off);
  }
  if (lane == 0) Mout[(size_t)bh * L + l] = mx - sm * (1.0f / (float)L);
}

// ============ top-k (U=45) per (b,h) ============
__global__ __launch_bounds__(256) void topk_kernel(
    const float* __restrict__ Mbuf, int* __restrict__ topk, int* __restrict__ map)
{
  int bh = blockIdx.x;
  int tid = threadIdx.x;
  __shared__ float vals[L];
  __shared__ float rv[256];
  __shared__ int ri[256];
  for (int i = tid; i < L; i += 256) {
    vals[i] = Mbuf[(size_t)bh * L + i];
    map[(size_t)bh * L + i] = -1;
  }
  __syncthreads();
  for (int u = 0; u < U; ++u) {
    float bv = -INFINITY;
    int bi = 1 << 30;
    for (int i = tid; i < L; i += 256) {
      float v = vals[i];
      if (v > bv || (v == bv && i < bi)) { bv = v; bi = i; }
    }
    rv[tid] = bv; ri[tid] = bi;
    __syncthreads();
    for (int s = 128; s > 0; s >>= 1) {
      if (tid < s) {
        float ov = rv[tid + s]; int oi = ri[tid + s];
        if (ov > rv[tid] || (ov == rv[tid] && oi < ri[tid])) { rv[tid] = ov; ri[tid] = oi; }
      }
      __syncthreads();
    }
    if (tid == 0) {
      int p = ri[0];
      topk[bh * U + u] = p;
      map[(size_t)bh * L + p] = u;
      vals[p] = -INFINITY;
    }
    __syncthreads();
  }
}

// ==== flash-decoding attn: per (b,h,split) partials via MFMA ====
__global__ __launch_bounds__(256) void attn_partial(
    const float* __restrict__ Q, const float* __restrict__ Kmat,
    const float* __restrict__ V, const int* __restrict__ topk,
    float* __restrict__ Opart, float* __restrict__ Mpart, float* __restrict__ Lpart)
{
  __shared__ __align__(16) unsigned short qs[UPAD][QROW];
  __shared__ __align__(16) unsigned short Ks[TILE][QROW];
  __shared__ __align__(16) unsigned short Vt[DH][QROW];
  __shared__ __align__(16) unsigned short ps[4][16][QROW];
  __shared__ int ms[UPAD];

  int tid = threadIdx.x;
  int bh = blockIdx.x / NSPLIT;
  int s  = blockIdx.x % NSPLIT;
  int kstart = s * SLEN;

  {
    int u = tid & 63, c = tid >> 6;
    if (u < UPAD) {
      int mu = (u < U) ? topk[bh * U + u] : -1;
      if (c == 0) ms[u] = mu;
      unsigned int pk[8];
      if (mu >= 0) {
        const float4* src = (const float4*)(Q + ((size_t)bh * L + mu) * DH + c * 16);
#pragma unroll
        for (int j = 0; j < 4; ++j) {
          float4 f = src[j];
          pk[j * 2 + 0] = (unsigned)f2bf(f.x) | ((unsigned)f2bf(f.y) << 16);
          pk[j * 2 + 1] = (unsigned)f2bf(f.z) | ((unsigned)f2bf(f.w) << 16);
        }
      } else {
#pragma unroll
        for (int j = 0; j < 8; ++j) pk[j] = 0;
      }
      uint4* dst = (uint4*)&qs[u][c * 16];
      dst[0] = make_uint4(pk[0], pk[1], pk[2], pk[3]);
      dst[1] = make_uint4(pk[4], pk[5], pk[6], pk[7]);
    }
  }
  __syncthreads();

  int bmax = -1;
  for (int i = 0; i < UPAD; ++i) bmax = max(bmax, ms[i]);
  int kend = min(SLEN, bmax + 1 - kstart);
  int ntiles = (kend > 0) ? (kend + TILE - 1) / TILE : 0;

  int lane = tid & 63;
  int w = tid >> 6;
  int ubase = w * 16;
  int col = lane & 15;
  int quad = lane >> 4;

  int mrow[4];
  float Mr[4], Lr[4];
  f32x4 Oacc[4];
#pragma unroll
  for (int ng = 0; ng < 4; ++ng) Oacc[ng] = (f32x4){0.f, 0.f, 0.f, 0.f};
#pragma unroll
  for (int r = 0; r < 4; ++r) {
    int uu = ubase + quad * 4 + r;
    mrow[r] = (w < 3) ? ms[uu] : -1;
    Mr[r] = -1e30f; Lr[r] = 0.f;
  }
  int gq = max(max(mrow[0], mrow[1]), max(mrow[2], mrow[3]));
  gq = max(gq, __shfl_xor(gq, 16));
  gq = max(gq, __shfl_xor(gq, 32));

  for (int t = 0; t < ntiles; ++t) {
    int k0 = kstart + t * TILE;
    __syncthreads();
    {
      int kr = tid & 63, dc = tid >> 6;
      const float4* ksrc = (const float4*)(Kmat + ((size_t)bh * L + k0 + kr) * DH + dc * 16);
      unsigned int pk[8];
#pragma unroll
      for (int j = 0; j < 4; ++j) {
        float4 f = ksrc[j];
        pk[j * 2 + 0] = (unsigned)f2bf(f.x) | ((unsigned)f2bf(f.y) << 16);
        pk[j * 2 + 1] = (unsigned)f2bf(f.z) | ((unsigned)f2bf(f.w) << 16);
      }
      uint4* kd = (uint4*)&Ks[kr][dc * 16];
      kd[0] = make_uint4(pk[0], pk[1], pk[2], pk[3]);
      kd[1] = make_uint4(pk[4], pk[5], pk[6], pk[7]);
      const float4* vsrc = (const float4*)(V + ((size_t)bh * L + k0 + kr) * DH + dc * 16);
#pragma unroll
      for (int j = 0; j < 4; ++j) {
        float4 f = vsrc[j];
        Vt[dc * 16 + j * 4 + 0][kr] = f2bf(f.x);
        Vt[dc * 16 + j * 4 + 1][kr] = f2bf(f.y);
        Vt[dc * 16 + j * 4 + 2][kr] = f2bf(f.z);
        Vt[dc * 16 + j * 4 + 3][kr] = f2bf(f.w);
      }
    }
    __syncthreads();
    if (w == 3 || k0 > gq) continue;

    f32x4 sacc[4];
#pragma unroll
    for (int ng = 0; ng < 4; ++ng) sacc[ng] = (f32x4){0.f, 0.f, 0.f, 0.f};
#pragma unroll
    for (int kg = 0; kg < 2; ++kg) {
      short8 af = *(const short8*)&qs[ubase + col][kg * 32 + quad * 8];
#pragma unroll
      for (int ng = 0; ng < 4; ++ng) {
        short8 bf_ = *(const short8*)&Ks[ng * 16 + col][kg * 32 + quad * 8];
        sacc[ng] = __builtin_amdgcn_mfma_f32_16x16x32_bf16(af, bf_, sacc[ng], 0, 0, 0);
      }
    }
#pragma unroll
    for (int r = 0; r < 4; ++r) {
      int mu = mrow[r];
      float msv[4];
      float tm = -1e30f;
#pragma unroll
      for (int ng = 0; ng < 4; ++ng) {
        int kpos = k0 + ng * 16 + col;
        float sv = (kpos <= mu) ? sacc[ng][r] * 0.125f : -1e30f;
        msv[ng] = sv;
        tm = fmaxf(tm, sv);
      }
      tm = fmaxf(tm, __shfl_xor(tm, 1));
      tm = fmaxf(tm, __shfl_xor(tm, 2));
      tm = fmaxf(tm, __shfl_xor(tm, 4));
      tm = fmaxf(tm, __shfl_xor(tm, 8));
      float newM = fmaxf(Mr[r], tm);
      float alpha = __expf(Mr[r] - newM);
      float psum = 0.f;
      float pv[4];
#pragma unroll
      for (int ng = 0; ng < 4; ++ng) {
        float p = (msv[ng] > -1e29f) ? __expf(msv[ng] - newM) : 0.f;
        pv[ng] = p;
        psum += p;
      }
      psum += __shfl_xor(psum, 1);
      psum += __shfl_xor(psum, 2);
      psum += __shfl_xor(psum, 4);
      psum += __shfl_xor(psum, 8);
      Lr[r] = Lr[r] * alpha + psum;
      Mr[r] = newM;
#pragma unroll
      for (int ng = 0; ng < 4; ++ng) Oacc[ng][r] *= alpha;
#pragma unroll
      for (int ng = 0; ng < 4; ++ng)
        ps[w][quad * 4 + r][ng * 16 + col] = f2bf(pv[ng]);
    }
#pragma unroll
    for (int kg = 0; kg < 2; ++kg) {
      short8 pf = *(const short8*)&ps[w][col][kg * 32 + quad * 8];
#pragma unroll
      for (int ng = 0; ng < 4; ++ng) {
        short8 vf = *(const short8*)&Vt[ng * 16 + col][kg * 32 + quad * 8];
        Oacc[ng] = __builtin_amdgcn_mfma_f32_16x16x32_bf16(pf, vf, Oacc[ng], 0, 0, 0);
      }
    }
  }

  if (w < 3) {
    size_t base = ((size_t)bh * NSPLIT + s) * UPAD;
#pragma unroll
    for (int r = 0; r < 4; ++r) {
      int uu = ubase + quad * 4 + r;
#pragma unroll
      for (int ng = 0; ng < 4; ++ng)
        Opart[(base + uu) * DH + ng * 16 + col] = Oacc[ng][r];
      if (col == 0) { Mpart[base + uu] = Mr[r]; Lpart[base + uu] = Lr[r]; }
    }
  }
}

// ==== combine split partials -> upd ====
__global__ __launch_bounds__(256) void attn_combine(
    const float* __restrict__ Opart, const float* __restrict__ Mpart,
    const float* __restrict__ Lpart, float* __restrict__ upd)
{
  int idx = blockIdx.x * 4 + (threadIdx.x >> 6);
  int lane = threadIdx.x & 63;
  int bh = idx / U, u = idx % U;
  size_t base = (size_t)bh * NSPLIT * UPAD + u;
  float Ms[NSPLIT];
  float Mg = -1e30f;
#pragma unroll
  for (int ss = 0; ss < NSPLIT; ++ss) {
    Ms[ss] = Mpart[base + ss * UPAD];
    Mg = fmaxf(Mg, Ms[ss]);
  }
  float acc = 0.f, lsum = 0.f;
#pragma unroll
  for (int ss = 0; ss < NSPLIT; ++ss) {
    float wgt = __expf(Ms[ss] - Mg);
    acc += wgt * Opart[(base + ss * UPAD) * DH + lane];
    lsum += wgt * Lpart[base + ss * UPAD];
  }
  upd[((size_t)bh * U + u) * DH + lane] = acc / lsum;
}

// ================= cumsum(V) + scatter =================
__global__ __launch_bounds__(256) void cumsum_p1(const float* __restrict__ V, float* __restrict__ chunks)
{
  int wid = blockIdx.x * 4 + (threadIdx.x >> 6);
  int lane = threadIdx.x & 63;
  int c = wid & (NCH - 1);
  int bh = wid >> 4;
  const float* vb = V + ((size_t)bh * L + c * CHUNK) * DH + lane;
  float s = 0.f;
  for (int j = 0; j < CHUNK; ++j) s += vb[(size_t)j * DH];
  chunks[((size_t)bh * NCH + c) * DH + lane] = s;
}

__global__ __launch_bounds__(256) void cumsum_p2(float* __restrict__ chunks)
{
  int t = blockIdx.x * 256 + threadIdx.x;
  int bh = t >> 6;
  int d = t & 63;
  float run = 0.f;
  for (int c = 0; c < NCH; ++c) {
    size_t idx = ((size_t)bh * NCH + c) * DH + d;
    float v = chunks[idx];
    chunks[idx] = run;
    run += v;
  }
}

__global__ __launch_bounds__(256) void cumsum_p3(
    const float* __restrict__ V, const float* __restrict__ chunks,
    const int* __restrict__ map, const float* __restrict__ upd,
    float* __restrict__ ctx)
{
  int wid = blockIdx.x * 4 + (threadIdx.x >> 6);
  int lane = threadIdx.x & 63;
  int c = wid & (NCH - 1);
  int bh = wid >> 4;
  int b_ = bh / H, h = bh % H;
  float acc = chunks[((size_t)bh * NCH + c) * DH + lane];
  const float* vb = V + ((size_t)bh * L + c * CHUNK) * DH + lane;
  for (int j = 0; j < CHUNK; ++j) {
    int pos = c * CHUNK + j;
    acc += vb[(size_t)j * DH];
    int uu = map[(size_t)bh * L + pos];
    float val = (uu >= 0) ? upd[((size_t)bh * U + uu) * DH + lane] : acc;
    ctx[((size_t)b_ * L + pos) * DM + h * DH + lane] = val;
  }
}

// ============================ launch ============================
extern "C" void kernel_launch(void* const* d_in, const int* in_sizes, int n_in,
                              void* d_out, int out_size, void* d_ws, size_t ws_size,
                              hipStream_t stream) {
  const float* x   = (const float*)d_in[0];
  const int* sidx  = (const int*)d_in[1];
  const float* Wq  = (const float*)d_in[2];
  const float* bq  = (const float*)d_in[3];
  const float* Wk  = (const float*)d_in[4];
  const float* bk  = (const float*)d_in[5];
  const float* Wv  = (const float*)d_in[6];
  const float* bv  = (const float*)d_in[7];
  const float* Wo  = (const float*)d_in[8];
  const float* bo  = (const float*)d_in[9];
  float* out = (float*)d_out;

  const size_t NQKV = (size_t)B * H * L * DH;

  float* Q    = (float*)d_ws;          // 134 MB, reused as ctx after attn
  float* Kb   = Q + NQKV;              // 134 MB
  float* Mbuf = Kb + NQKV;
  int* map    = (int*)(Mbuf + (size_t)B * H * L);
  int* topk   = map + (size_t)B * H * L;
  float* upd  = (float*)(topk + ((B * H * U + 63) & ~63));
  float* chunks = upd + (size_t)B * H * U * DH;
  float* Opart  = chunks + (size_t)B * H * NCH * DH;
  float* Mpart  = Opart + (size_t)B * H * NSPLIT * UPAD * DH;
  float* Lpart  = Mpart + (size_t)B * H * NSPLIT * UPAD;
  float* V    = out;                   // alias d_out as V scratch
  float* ctx  = Q;                     // alias Q buffer as ctx

  gemm_kernel<<<8192, 256, 0, stream>>>(x, Wq, bq, Q, 1);      // fp32 (selection)
  gemm_kernel<<<8192, 256, 0, stream>>>(x, Wk, bk, Kb, 1);     // fp32 (selection)
  mfma_gemm<<<2048, 256, 0, stream>>>(x, Wv, bv, V, 1);        // bf16 MFMA (value)
  mscore_kernel<<<(B * H * L) / 4, 256, 0, stream>>>(Q, Kb, sidx, Mbuf);
  topk_kernel<<<B * H, 256, 0, stream>>>(Mbuf, topk, map);
  attn_partial<<<B * H * NSPLIT, 256, 0, stream>>>(Q, Kb, V, topk, Opart, Mpart, Lpart);
  attn_combine<<<(B * H * U) / 4, 256, 0, stream>>>(Opart, Mpart, Lpart, upd);
  cumsum_p1<<<(B * H * NCH) / 4, 256, 0, stream>>>(V, chunks);
  cumsum_p2<<<(B * H * DH) / 256, 256, 0, stream>>>(chunks);
  cumsum_p3<<<(B * H * NCH) / 4, 256, 0, stream>>>(V, chunks, map, upd, ctx);
  mfma_gemm<<<2048, 256, 0, stream>>>(ctx, Wo, bo, out, 0);    // bf16 MFMA (value)
}